// Round 6
// baseline (119.020 us; speedup 1.0000x reference)
//
#include <hip/hip_runtime.h>
#include <math.h>

// K0: WphiT[k][dd] = Wphi[dd][k]  (128x512 fp32, 256 KB)
__global__ void transpose_wphi_k(const float* __restrict__ wphi,
                                 float* __restrict__ wphiT) {
  int idx = blockIdx.x * 256 + threadIdx.x;   // 0..65535
  int k  = idx >> 9;
  int dd = idx & 511;
  wphiT[idx] = wphi[dd * 128 + k];
}

__device__ __forceinline__ void fma4(float4& a, float s, const float4& w) {
  a.x = fmaf(s, w.x, a.x);
  a.y = fmaf(s, w.y, a.y);
  a.z = fmaf(s, w.z, a.z);
  a.w = fmaf(s, w.w, a.w);
}

__device__ __forceinline__ float wave_sum(float v) {
  v += __shfl_xor(v, 32, 64);
  v += __shfl_xor(v, 16, 64);
  v += __shfl_xor(v,  8, 64);
  v += __shfl_xor(v,  4, 64);
  v += __shfl_xor(v,  2, 64);
  v += __shfl_xor(v,  1, 64);
  return v;
}

// 1024 blocks x 256 thr (4 waves) = 4 blocks/CU, 16 waves/CU. 4 rows/block.
// 3 barriers total; between barriers every wave runs an independent,
// deeply-unrolled load+FMA stream (weights from L2, wave-sliced so each
// block reads each weight matrix exactly once).
// LDS floats: As[4][512] @0 (8KB) | qS[4][128] @2048 (2KB) | uS[4][512] @2560 (8KB)
__launch_bounds__(256, 4)
__global__ void entity_attn_k(const float* __restrict__ A,     // (4096,512)
                              const float* __restrict__ V,     // (4096,16,512)
                              const float* __restrict__ Wpsi,  // (512,128)
                              const float* __restrict__ WphiT, // (128,512) ws
                              float* __restrict__ Out)         // (4096,16)
{
  __shared__ __align__(16) float S[4608];   // 18 KB
  const int tid  = threadIdx.x;
  const int lane = tid & 63;
  const int w    = tid >> 6;                // wave 0..3
  const int g0   = blockIdx.x * 4;

  // ---- stage A: 4 rows, coalesced f4 ----
  {
    const float4* src = (const float4*)(A + (size_t)g0 * 512);
    float4* dst = (float4*)S;
    dst[tid]       = src[tid];
    dst[tid + 256] = src[tid + 256];
  }
  __syncthreads();

  // ---- phase Q: q[r][k] = sum_d A[r][d] Wpsi[d][k] ----
  // wave w owns k-slice [32w, 32w+32). lane: r = l>>4, k-pair kk = (l&15)*2.
  {
    const int r    = lane >> 4;
    const int kcol = w * 32 + (lane & 15) * 2;
    const int kh   = kcol >> 1;
    float q0 = 0.f, q1 = 0.f;
    const float4* ar  = (const float4*)(S + r * 512);
    const float2* wp2 = (const float2*)Wpsi;   // [d][64 pairs]
#pragma unroll 4
    for (int d4 = 0; d4 < 128; ++d4) {
      float4 a4 = ar[d4];                       // LDS broadcast (4 addrs/wave)
      float2 w0 = wp2[(d4 * 4 + 0) * 64 + kh];  // 128B/wave unique, L2
      float2 w1 = wp2[(d4 * 4 + 1) * 64 + kh];
      float2 w2 = wp2[(d4 * 4 + 2) * 64 + kh];
      float2 w3 = wp2[(d4 * 4 + 3) * 64 + kh];
      q0 = fmaf(a4.x, w0.x, q0); q1 = fmaf(a4.x, w0.y, q1);
      q0 = fmaf(a4.y, w1.x, q0); q1 = fmaf(a4.y, w1.y, q1);
      q0 = fmaf(a4.z, w2.x, q0); q1 = fmaf(a4.z, w2.y, q1);
      q0 = fmaf(a4.w, w3.x, q0); q1 = fmaf(a4.w, w3.y, q1);
    }
    ((float2*)(S + 2048))[(r * 128 + kcol) >> 1] = make_float2(q0, q1);
  }
  __syncthreads();

  // ---- phase U: u[r][dd] = sum_k q[r][k] WphiT[k][dd] ----
  // wave w owns dd-slice [128w, 128w+128). lane: r = l>>4, 8 dd = (l&15)*8.
  {
    const int r   = lane >> 4;
    const int dd0 = w * 128 + (lane & 15) * 8;
    float4 u0 = make_float4(0.f, 0.f, 0.f, 0.f);
    float4 u1 = u0;
    const float4* qr = (const float4*)(S + 2048 + r * 128);
    const float4* wt = (const float4*)WphiT;   // [k][128 f4]
#pragma unroll 2
    for (int k4 = 0; k4 < 32; ++k4) {
      float4 q4 = qr[k4];                      // LDS broadcast (4 addrs/wave)
#pragma unroll
      for (int j = 0; j < 4; ++j) {
        const int k = k4 * 4 + j;
        float4 wa = wt[(k * 512 + dd0) >> 2];  // 512B/wave unique, L2
        float4 wb = wt[((k * 512 + dd0) >> 2) + 1];
        float qv = (j == 0) ? q4.x : (j == 1) ? q4.y : (j == 2) ? q4.z : q4.w;
        fma4(u0, qv, wa);
        fma4(u1, qv, wb);
      }
    }
    float4* uS4 = (float4*)(S + 2560);
    uS4[(r * 512 + dd0) >> 2]       = u0;
    uS4[((r * 512 + dd0) >> 2) + 1] = u1;
  }
  __syncthreads();

  // ---- phase V: wave w streams row g0+w; beta = u.v; softmax over 16 a ----
  {
    const float4* ur = (const float4*)(S + 2560 + w * 512);
    const float4 uf0 = ur[2 * lane];
    const float4 uf1 = ur[2 * lane + 1];
    const float4* vrow = (const float4*)V + (size_t)(g0 + w) * 2048;

    float acc[16];
#pragma unroll
    for (int ag = 0; ag < 2; ++ag) {
      float4 va[16];
#pragma unroll
      for (int j = 0; j < 8; ++j) {
        va[j * 2]     = vrow[(size_t)(ag * 8 + j) * 128 + 2 * lane];
        va[j * 2 + 1] = vrow[(size_t)(ag * 8 + j) * 128 + 2 * lane + 1];
      }
#pragma unroll
      for (int j = 0; j < 8; ++j) {
        float s;
        s = va[j*2].x * uf0.x;
        s = fmaf(va[j*2].y,   uf0.y, s);
        s = fmaf(va[j*2].z,   uf0.z, s);
        s = fmaf(va[j*2].w,   uf0.w, s);
        s = fmaf(va[j*2+1].x, uf1.x, s);
        s = fmaf(va[j*2+1].y, uf1.y, s);
        s = fmaf(va[j*2+1].z, uf1.z, s);
        s = fmaf(va[j*2+1].w, uf1.w, s);
        acc[ag * 8 + j] = s;
      }
    }

#pragma unroll
    for (int a = 0; a < 16; ++a) acc[a] = wave_sum(acc[a]);

    float mx = acc[0];
#pragma unroll
    for (int a = 1; a < 16; ++a) mx = fmaxf(mx, acc[a]);
    float ss = 0.f;
#pragma unroll
    for (int a = 0; a < 16; ++a) { acc[a] = __expf(acc[a] - mx); ss += acc[a]; }
    const float inv = 1.0f / ss;

    if (lane == 0) {
      float4* o4 = (float4*)(Out + (size_t)(g0 + w) * 16);
      o4[0] = make_float4(acc[0]*inv,  acc[1]*inv,  acc[2]*inv,  acc[3]*inv);
      o4[1] = make_float4(acc[4]*inv,  acc[5]*inv,  acc[6]*inv,  acc[7]*inv);
      o4[2] = make_float4(acc[8]*inv,  acc[9]*inv,  acc[10]*inv, acc[11]*inv);
      o4[3] = make_float4(acc[12]*inv, acc[13]*inv, acc[14]*inv, acc[15]*inv);
    }
  }
}

extern "C" void kernel_launch(void* const* d_in, const int* in_sizes, int n_in,
                              void* d_out, int out_size, void* d_ws, size_t ws_size,
                              hipStream_t stream) {
  (void)in_sizes; (void)n_in; (void)out_size; (void)ws_size;
  const float* A    = (const float*)d_in[0];  // agent_observation (128,32,512)
  const float* V    = (const float*)d_in[1];  // visible_observations (128,32,16,512)
  const float* Wpsi = (const float*)d_in[2];  // (512,128)
  const float* Wphi = (const float*)d_in[3];  // (512,128)
  float* Out   = (float*)d_out;               // (4096,16) fp32
  float* WphiT = (float*)d_ws;                // 256 KB

  transpose_wphi_k<<<256, 256, 0, stream>>>(Wphi, WphiT);
  entity_attn_k<<<1024, 256, 0, stream>>>(A, V, Wpsi, WphiT, Out);
}

// Round 7
// 77.932 us; speedup vs baseline: 1.5272x; 1.5272x over previous
//
#include <hip/hip_runtime.h>
#include <math.h>

// ---------------- K0: WphiT[k][dd] = Wphi[dd][k] (128x512 fp32, 256 KB) ----
__global__ void transpose_wphi_k(const float* __restrict__ wphi,
                                 float* __restrict__ wphiT) {
  int idx = blockIdx.x * 256 + threadIdx.x;   // 0..65535
  int k  = idx >> 9;
  int dd = idx & 511;
  wphiT[idx] = wphi[dd * 128 + k];
}

__device__ __forceinline__ void fma4(float4& a, float s, const float4& w) {
  a.x = fmaf(s, w.x, a.x);
  a.y = fmaf(s, w.y, a.y);
  a.z = fmaf(s, w.z, a.z);
  a.w = fmaf(s, w.w, a.w);
}

__device__ __forceinline__ float wave_sum(float v) {
  v += __shfl_xor(v, 32, 64);
  v += __shfl_xor(v, 16, 64);
  v += __shfl_xor(v,  8, 64);
  v += __shfl_xor(v,  4, 64);
  v += __shfl_xor(v,  2, 64);
  v += __shfl_xor(v,  1, 64);
  return v;
}

// ---------------- K1: Q[g][k] = sum_d A[g][d] * Wpsi[d][k] -----------------
// 256 blocks x 512 thr, 16 rows/block. Wave w owns k-f4 slice {4w..4w+3}
// -> each block reads Wpsi exactly once (67 MB aggregate L2).
// thread: kq = t>>4 (k-f4), r = t&15 (row). At[d][r] stride 17 (bank-clean).
__launch_bounds__(512, 2)
__global__ void q_k(const float* __restrict__ A,     // (4096,512)
                    const float* __restrict__ Wpsi,  // (512,128)
                    float* __restrict__ Q)           // (4096,128)
{
  __shared__ __align__(16) float At[512 * 17];   // 34 KB
  const int tid = threadIdx.x;
  const int g0  = blockIdx.x * 16;

  // stage A transposed: t -> (r = t>>5, j0 = t&31), 4 f4 per thread
  {
    const int r  = tid >> 5;
    const int j0 = tid & 31;
    const float4* a4 = (const float4*)(A + (size_t)(g0 + r) * 512);
#pragma unroll
    for (int m = 0; m < 4; ++m) {
      const int j = j0 + 32 * m;
      float4 v = a4[j];
      At[(4 * j + 0) * 17 + r] = v.x;
      At[(4 * j + 1) * 17 + r] = v.y;
      At[(4 * j + 2) * 17 + r] = v.z;
      At[(4 * j + 3) * 17 + r] = v.w;
    }
  }
  __syncthreads();

  {
    const int kq = tid >> 4;     // k f4-group 0..31 (wave-sliced: 4w+(l>>4))
    const int r  = tid & 15;     // row
    float4 acc0 = make_float4(0.f, 0.f, 0.f, 0.f);
    float4 acc1 = acc0, acc2 = acc0, acc3 = acc0;
    const float4* wp4 = (const float4*)Wpsi;
#pragma unroll 4
    for (int d4 = 0; d4 < 128; ++d4) {
      const int d = d4 * 4;
      float a0 = At[(d + 0) * 17 + r];
      float a1 = At[(d + 1) * 17 + r];
      float a2 = At[(d + 2) * 17 + r];
      float a3 = At[(d + 3) * 17 + r];
      fma4(acc0, a0, wp4[(d + 0) * 32 + kq]);
      fma4(acc1, a1, wp4[(d + 1) * 32 + kq]);
      fma4(acc2, a2, wp4[(d + 2) * 32 + kq]);
      fma4(acc3, a3, wp4[(d + 3) * 32 + kq]);
    }
    acc0.x += acc1.x + acc2.x + acc3.x;
    acc0.y += acc1.y + acc2.y + acc3.y;
    acc0.z += acc1.z + acc2.z + acc3.z;
    acc0.w += acc1.w + acc2.w + acc3.w;
    ((float4*)Q)[(size_t)(g0 + r) * 32 + kq] = acc0;
  }
}

// ---------------- K2: U[g][dd] = sum_k Q[g][k] * WphiT[k][dd] --------------
// 256 blocks x 512 thr, 16 rows/block. Wave w owns dd-f4 slice [16w,16w+16)
// -> each block reads WphiT exactly once (67 MB aggregate L2).
// thread: ddq = t>>2 (dd-f4), rq = t&3 (4 rows rq*4..+4). Qt stride 20.
__launch_bounds__(512, 2)
__global__ void u_k(const float* __restrict__ Q,      // (4096,128)
                    const float* __restrict__ WphiT,  // (128,512)
                    float* __restrict__ U)            // (4096,512)
{
  __shared__ __align__(16) float Qt[128 * 20];   // 10 KB
  const int tid = threadIdx.x;
  const int g0  = blockIdx.x * 16;

  // stage Q transposed: t -> (r = t>>5, j = t&31), 1 f4 per thread
  {
    const int r = tid >> 5;
    const int j = tid & 31;
    float4 v = ((const float4*)Q)[(size_t)(g0 + r) * 32 + j];
    Qt[(4 * j + 0) * 20 + r] = v.x;
    Qt[(4 * j + 1) * 20 + r] = v.y;
    Qt[(4 * j + 2) * 20 + r] = v.z;
    Qt[(4 * j + 3) * 20 + r] = v.w;
  }
  __syncthreads();

  {
    const int ddq = tid >> 2;   // dd f4-group 0..127 (wave-sliced: 16w+(l>>2))
    const int rq  = tid & 3;    // row group: rows rq*4 .. rq*4+3
    float4 acc[4];
#pragma unroll
    for (int i = 0; i < 4; ++i) acc[i] = make_float4(0.f, 0.f, 0.f, 0.f);
    const float4* wt4 = (const float4*)WphiT;
#pragma unroll 8
    for (int k = 0; k < 128; ++k) {
      float4 wt = wt4[(size_t)k * 128 + ddq];             // 256B/wave unique
      float4 q  = *(const float4*)(Qt + k * 20 + rq * 4); // LDS broadcast
      fma4(acc[0], q.x, wt);
      fma4(acc[1], q.y, wt);
      fma4(acc[2], q.z, wt);
      fma4(acc[3], q.w, wt);
    }
    float4* U4 = (float4*)U;
#pragma unroll
    for (int i = 0; i < 4; ++i)
      U4[(size_t)(g0 + rq * 4 + i) * 128 + ddq] = acc[i];
  }
}

// ---------------- K3: pure stream: beta = u.v, softmax over 16 a -----------
// 1024 blocks x 256 thr; wave = one (b,e) row. No LDS, no barriers.
__launch_bounds__(256)
__global__ void stream_k(const float* __restrict__ V,   // (4096,16,512)
                         const float* __restrict__ U,   // (4096,512)
                         float* __restrict__ Out)       // (4096,16)
{
  const int lane = threadIdx.x & 63;
  const int w    = threadIdx.x >> 6;
  const size_t g = (size_t)blockIdx.x * 4 + w;

  const float4* vrow = (const float4*)V + g * 2048;  // 16 x 128 f4
  const float4* ur   = (const float4*)U + g * 128;
  const float4 uf0 = ur[2 * lane];
  const float4 uf1 = ur[2 * lane + 1];

  float acc[16];
#pragma unroll
  for (int ag = 0; ag < 2; ++ag) {
    float4 va[16];
#pragma unroll
    for (int j = 0; j < 8; ++j) {
      va[j * 2]     = vrow[(size_t)(ag * 8 + j) * 128 + 2 * lane];
      va[j * 2 + 1] = vrow[(size_t)(ag * 8 + j) * 128 + 2 * lane + 1];
    }
#pragma unroll
    for (int j = 0; j < 8; ++j) {
      float s;
      s = va[j*2].x * uf0.x;
      s = fmaf(va[j*2].y,   uf0.y, s);
      s = fmaf(va[j*2].z,   uf0.z, s);
      s = fmaf(va[j*2].w,   uf0.w, s);
      s = fmaf(va[j*2+1].x, uf1.x, s);
      s = fmaf(va[j*2+1].y, uf1.y, s);
      s = fmaf(va[j*2+1].z, uf1.z, s);
      s = fmaf(va[j*2+1].w, uf1.w, s);
      acc[ag * 8 + j] = s;
    }
  }

#pragma unroll
  for (int a = 0; a < 16; ++a) acc[a] = wave_sum(acc[a]);

  float mx = acc[0];
#pragma unroll
  for (int a = 1; a < 16; ++a) mx = fmaxf(mx, acc[a]);
  float ss = 0.f;
#pragma unroll
  for (int a = 0; a < 16; ++a) { acc[a] = __expf(acc[a] - mx); ss += acc[a]; }
  const float inv = 1.0f / ss;

  if (lane == 0) {
    float4* o4 = (float4*)(Out + g * 16);
    o4[0] = make_float4(acc[0]*inv,  acc[1]*inv,  acc[2]*inv,  acc[3]*inv);
    o4[1] = make_float4(acc[4]*inv,  acc[5]*inv,  acc[6]*inv,  acc[7]*inv);
    o4[2] = make_float4(acc[8]*inv,  acc[9]*inv,  acc[10]*inv, acc[11]*inv);
    o4[3] = make_float4(acc[12]*inv, acc[13]*inv, acc[14]*inv, acc[15]*inv);
  }
}

extern "C" void kernel_launch(void* const* d_in, const int* in_sizes, int n_in,
                              void* d_out, int out_size, void* d_ws, size_t ws_size,
                              hipStream_t stream) {
  (void)in_sizes; (void)n_in; (void)out_size; (void)ws_size;
  const float* A    = (const float*)d_in[0];  // agent_observation (128,32,512)
  const float* V    = (const float*)d_in[1];  // visible_observations (128,32,16,512)
  const float* Wpsi = (const float*)d_in[2];  // (512,128)
  const float* Wphi = (const float*)d_in[3];  // (512,128)
  float* Out = (float*)d_out;                 // (4096,16) fp32

  float* WphiT = (float*)d_ws;                       // 256 KB
  float* Q     = (float*)d_ws + 65536;               // 2 MB
  float* U     = (float*)d_ws + 65536 + 524288;      // 8 MB

  transpose_wphi_k<<<256, 256, 0, stream>>>(Wphi, WphiT);
  q_k<<<256, 512, 0, stream>>>(A, Wpsi, Q);
  u_k<<<256, 512, 0, stream>>>(Q, WphiT, U);
  stream_k<<<1024, 256, 0, stream>>>(V, U, Out);
}

// Round 8
// 51.445 us; speedup vs baseline: 2.3136x; 1.5149x over previous
//
#include <hip/hip_runtime.h>
#include <math.h>

#define OBS 512
#define ATT 128
#define RPB 4   // (b,e) rows per block

// Kernel 0: ws <- Wphi^T  (WphiT[k][dd] = Wphi[dd][k]), 128x512 fp32 = 256KB
__global__ void transpose_wphi_k(const float* __restrict__ wphi,
                                 float* __restrict__ wphiT) {
  int idx = blockIdx.x * 256 + threadIdx.x;   // 0..65535
  int k  = idx >> 9;
  int dd = idx & 511;
  wphiT[idx] = wphi[dd * ATT + k];
}

__device__ __forceinline__ void fma4(float4& a, float s, float4 w) {
  a.x = fmaf(s, w.x, a.x);
  a.y = fmaf(s, w.y, a.y);
  a.z = fmaf(s, w.z, a.z);
  a.w = fmaf(s, w.w, a.w);
}

// 4 blocks/CU x 4 waves = 16 waves/CU target occupancy
__launch_bounds__(256, 4)
__global__ void entity_attn_k(const float* __restrict__ A,     // (4096,512)
                              const float* __restrict__ V,     // (4096,16,512)
                              const float* __restrict__ Wpsi,  // (512,128)
                              const float* __restrict__ WphiT, // (128,512) ws
                              float* __restrict__ Out)         // (4096,16)
{
  // S layout (floats), 26KB total:
  //  [0,2048):    At[d][4]    (stage -> B)   THEN uS[4][512] (C -> D)
  //  [2048,6144): qpart[ds8][r4][k128]  (B -> reduce)
  //  [6144,6656): qt[k][4]    (reduce -> C)
  __shared__ __align__(16) float S[6656];

  const int tid  = threadIdx.x;
  const int lane = tid & 63;
  const int wave = tid >> 6;          // 0..3
  const int g0   = blockIdx.x * RPB;

  // ---- stage A transposed: At[d][r] = A[g0+r][d] ----
  {
    const int r = tid & 3;
    const int c = tid >> 2;           // 0..63
    const float4* a4 = (const float4*)(A + (size_t)(g0 + r) * OBS) + c * 2;
    float4 v0 = a4[0], v1 = a4[1];
    const int d0 = c * 8;
    S[(d0+0)*4+r] = v0.x; S[(d0+1)*4+r] = v0.y;
    S[(d0+2)*4+r] = v0.z; S[(d0+3)*4+r] = v0.w;
    S[(d0+4)*4+r] = v1.x; S[(d0+5)*4+r] = v1.y;
    S[(d0+6)*4+r] = v1.z; S[(d0+7)*4+r] = v1.w;
  }
  __syncthreads();

  // ---- phase B: q partials. thread = (k-quad kg, d-split ds) ----
  // Wpsi read exactly once per block (coalesced float4), At via LDS broadcast.
  {
    const int kg = tid & 31;          // k0 = kg*4
    const int ds = tid >> 5;          // 0..7, d-range ds*64..+64
    float4 acc0 = make_float4(0.f,0.f,0.f,0.f);
    float4 acc1 = acc0, acc2 = acc0, acc3 = acc0;
    const float4* wp4 = (const float4*)Wpsi;
    const float4* at4 = (const float4*)S;
    const int dbase = ds * 64;
#pragma unroll 8
    for (int i = 0; i < 64; ++i) {
      const int d = dbase + i;
      float4 w = wp4[d * 32 + kg];    // Wpsi[d][k0..k0+4)
      float4 a = at4[d];              // At[d][0..4) — uniform-ish broadcast
      fma4(acc0, a.x, w);
      fma4(acc1, a.y, w);
      fma4(acc2, a.z, w);
      fma4(acc3, a.w, w);
    }
    float4* qp4 = (float4*)(S + 2048);
    qp4[(ds*4+0)*32 + kg] = acc0;
    qp4[(ds*4+1)*32 + kg] = acc1;
    qp4[(ds*4+2)*32 + kg] = acc2;
    qp4[(ds*4+3)*32 + kg] = acc3;
  }
  __syncthreads();

  // ---- q-reduce over 8 d-splits -> qt[k][4] ----
  {
#pragma unroll
    for (int e = tid; e < 512; e += 256) {
      const int r = e & 3;
      const int k = e >> 2;
      float s = 0.f;
#pragma unroll
      for (int ds = 0; ds < 8; ++ds) s += S[2048 + (ds*4 + r)*128 + k];
      S[6144 + k*4 + r] = s;
    }
  }
  __syncthreads();

  // ---- phase C: uS[r][dd] = sum_k qt[k][r] * WphiT[k][dd] ----
  // q via uniform LDS broadcast (no shuffles), WphiT coalesced scalar loads.
  {
    float acc[8] = {0.f,0.f,0.f,0.f,0.f,0.f,0.f,0.f};
    const float4* qt4 = (const float4*)(S + 6144);
#pragma unroll 4
    for (int k = 0; k < 128; ++k) {
      float w0 = WphiT[k*512 + tid];
      float w1 = WphiT[k*512 + tid + 256];
      float4 q = qt4[k];              // uniform address -> broadcast
      acc[0] = fmaf(q.x, w0, acc[0]);
      acc[1] = fmaf(q.y, w0, acc[1]);
      acc[2] = fmaf(q.z, w0, acc[2]);
      acc[3] = fmaf(q.w, w0, acc[3]);
      acc[4] = fmaf(q.x, w1, acc[4]);
      acc[5] = fmaf(q.y, w1, acc[5]);
      acc[6] = fmaf(q.z, w1, acc[6]);
      acc[7] = fmaf(q.w, w1, acc[7]);
    }
    // At is dead; overwrite S[0,2048) with u.
#pragma unroll
    for (int r = 0; r < 4; ++r) {
      S[r*512 + tid]       = acc[r];
      S[r*512 + tid + 256] = acc[4+r];
    }
  }
  __syncthreads();

  // ---- phase D: wave = one g-row; stream V (CONTIGUOUS per-instruction
  // addressing: lane l reads float4 #l and #(64+l) of each 512-float row),
  // beta = u.v, softmax over a ----
  {
    const int r = wave;
    const size_t g = (size_t)(g0 + r);
    const float4* vrow = (const float4*)V + g * 2048;   // 16 x 128 f4
    const float4* ur   = (const float4*)S + r * 128;
    const float4 uf0 = ur[lane];          // elements 4*lane .. 4*lane+3
    const float4 uf1 = ur[lane + 64];     // elements 256+4*lane ..
    float acc[16];
#pragma unroll
    for (int ag = 0; ag < 4; ++ag) {
      float4 lo[4], hi[4];
#pragma unroll
      for (int j = 0; j < 4; ++j) {
        lo[j] = vrow[(size_t)(ag*4 + j)*128 + lane];       // 1KB contiguous
        hi[j] = vrow[(size_t)(ag*4 + j)*128 + 64 + lane];  // 1KB contiguous
      }
#pragma unroll
      for (int j = 0; j < 4; ++j) {
        float s;
        s = lo[j].x * uf0.x;
        s = fmaf(lo[j].y, uf0.y, s);
        s = fmaf(lo[j].z, uf0.z, s);
        s = fmaf(lo[j].w, uf0.w, s);
        s = fmaf(hi[j].x, uf1.x, s);
        s = fmaf(hi[j].y, uf1.y, s);
        s = fmaf(hi[j].z, uf1.z, s);
        s = fmaf(hi[j].w, uf1.w, s);
        acc[ag*4 + j] = s;
      }
    }
#pragma unroll
    for (int a = 0; a < 16; ++a) {
      float v = acc[a];
      v += __shfl_xor(v, 32, 64);
      v += __shfl_xor(v, 16, 64);
      v += __shfl_xor(v,  8, 64);
      v += __shfl_xor(v,  4, 64);
      v += __shfl_xor(v,  2, 64);
      v += __shfl_xor(v,  1, 64);
      acc[a] = v;
    }
    float mx = acc[0];
#pragma unroll
    for (int a = 1; a < 16; ++a) mx = fmaxf(mx, acc[a]);
    float ssum = 0.f;
#pragma unroll
    for (int a = 0; a < 16; ++a) { acc[a] = __expf(acc[a] - mx); ssum += acc[a]; }
    const float inv = 1.0f / ssum;
    if (lane == 0) {
      float4* o4 = (float4*)(Out + g * 16);
      o4[0] = make_float4(acc[0]*inv,  acc[1]*inv,  acc[2]*inv,  acc[3]*inv);
      o4[1] = make_float4(acc[4]*inv,  acc[5]*inv,  acc[6]*inv,  acc[7]*inv);
      o4[2] = make_float4(acc[8]*inv,  acc[9]*inv,  acc[10]*inv, acc[11]*inv);
      o4[3] = make_float4(acc[12]*inv, acc[13]*inv, acc[14]*inv, acc[15]*inv);
    }
  }
}

extern "C" void kernel_launch(void* const* d_in, const int* in_sizes, int n_in,
                              void* d_out, int out_size, void* d_ws, size_t ws_size,
                              hipStream_t stream) {
  (void)in_sizes; (void)n_in; (void)out_size; (void)ws_size;
  const float* A    = (const float*)d_in[0];  // agent_observation (128,32,512)
  const float* V    = (const float*)d_in[1];  // visible_observations (128,32,16,512)
  const float* Wpsi = (const float*)d_in[2];  // (512,128)
  const float* Wphi = (const float*)d_in[3];  // (512,128)
  float* Out   = (float*)d_out;               // (4096,16) fp32
  float* WphiT = (float*)d_ws;                // 256KB scratch

  transpose_wphi_k<<<256, 256, 0, stream>>>(Wphi, WphiT);
  entity_attn_k<<<1024, 256, 0, stream>>>(A, V, Wpsi, WphiT, Out);
}